// Round 1
// baseline (319.609 us; speedup 1.0000x reference)
//
#include <hip/hip_runtime.h>
#include <stdint.h>

// Problem constants
#define NN   4000      // nodes
#define EE   64000     // edges
#define KSEL 32000     // top-k
#define LL   64        // MAX_LEN
#define INCH 256       // IN_CH = OUT_CH

// ---------------- workspace layout (bytes) ----------------
static constexpr size_t O_HIST  = 0;                        // 65536 * 4
static constexpr size_t O_META  = O_HIST + 262144;          // 64 * 4
static constexpr size_t O_MMAX  = O_META + 256;             // 4000*64*4
static constexpr size_t O_DEN   = O_MMAX + 1024000;         // 4000*64*4
static constexpr size_t ZERO_BYTES = O_DEN + 1024000;       // zeroed each call
static constexpr size_t O_KEYS  = ZERO_BYTES;               // 64000 * 8
static constexpr size_t O_CAND  = O_KEYS + 512000;          // 64000 * 4
static constexpr size_t O_SEL   = O_CAND + 256000;          // 64000 * 4
static constexpr size_t O_MEANB = O_SEL + 256000;           // 4000 * 8 (f64)
static constexpr size_t O_BMAT  = O_MEANB + 32000;          // 4000*64*4
static constexpr size_t O_V     = O_BMAT + 1024000;         // 4000*256*4
static constexpr size_t O_WG    = O_V + 4096000;            // 256*1024*4
static constexpr size_t O_P     = O_WG + 1048576;           // 256*64*4
static constexpr size_t O_C2    = O_P + 65536;              // 4000*64*4
static constexpr size_t O_WSUM1 = O_C2 + 1024000;           // 256*16*8 (f64)
static constexpr size_t O_WSUM2 = O_WSUM1 + 32768;          // 256*8 (f64)
static constexpr size_t O_BS1   = O_WSUM2 + 2048;           // 16*8 (f64)
static constexpr size_t O_CB    = O_BS1 + 128;              // 64*4
static constexpr size_t O_CONST = O_CB + 256;               // 8 (f64)

// order-preserving encodings
__device__ __forceinline__ unsigned encf(float f) {
  unsigned u = __float_as_uint(f);
  return (u & 0x80000000u) ? ~u : (u | 0x80000000u);
}
__device__ __forceinline__ float decf(unsigned e) {
  unsigned u = (e & 0x80000000u) ? (e & 0x7fffffffu) : ~e;
  return __uint_as_float(u);
}

// ---------------- K0: weight precontractions ----------------
// Wg[i][l*16+c]   = W_inc[i][l*32+c]                  (gathered, f32)
// P [i][l]        = sum_c W_inc[i][l*32+16+c]*p_t[l,c] (f32)
// Wsum1[i][c]     = sum_l W_inc[i][l*32+c]            (f64)
// wsum2[i]        = sum_l sum_c p_t[l,c]*W_inc[i][l*32+16+c] (f64)
// bs1[c]          = sum_l b_inc[l*32+c]               (f64)
// cb[l]           = sum_c p_t[l,c]*b_inc[l*32+16+c]   (f32), consts[0]=sum_l cb
__global__ void rk_prep(const float* __restrict__ W_inc, const float* __restrict__ p_t,
                        const float* __restrict__ b_inc,
                        float* __restrict__ Wg, float* __restrict__ P,
                        double* __restrict__ Wsum1, double* __restrict__ wsum2,
                        double* __restrict__ bs1, float* __restrict__ cb,
                        double* __restrict__ consts) {
  const int i = blockIdx.x;   // 0..255
  const int l = threadIdx.x;  // 0..63
  __shared__ double sred[64];
  const int base = i * 2048 + l * 32;
#pragma unroll
  for (int c = 0; c < 16; ++c) Wg[i * 1024 + l * 16 + c] = W_inc[base + c];
  double accP = 0.0;
#pragma unroll
  for (int c = 0; c < 16; ++c)
    accP += (double)W_inc[base + 16 + c] * (double)p_t[l * 16 + c];
  P[i * 64 + l] = (float)accP;
  sred[l] = accP;
  __syncthreads();
  if (l == 0) {
    double s = 0.0;
    for (int j = 0; j < 64; ++j) s += sred[j];
    wsum2[i] = s;
  }
  if (l < 16) {
    double s = 0.0;
    for (int l2 = 0; l2 < 64; ++l2) s += (double)W_inc[i * 2048 + l2 * 32 + l];
    Wsum1[i * 16 + l] = s;
  }
  if (i == 0) {
    __syncthreads();   // wsum2 sum done before sred reuse
    if (l < 16) {
      double s = 0.0;
      for (int l2 = 0; l2 < 64; ++l2) s += (double)b_inc[l2 * 32 + l];
      bs1[l] = s;
    }
    double cbv = 0.0;
#pragma unroll
    for (int c = 0; c < 16; ++c)
      cbv += (double)p_t[l * 16 + c] * (double)b_inc[l * 32 + 16 + c];
    cb[l] = (float)cbv;
    sred[l] = cbv;
    __syncthreads();
    if (l == 0) {
      double s = 0.0;
      for (int j = 0; j < 64; ++j) s += sred[j];
      consts[0] = s;
    }
  }
}

// ---------------- K1: meanB[n] in f64 (top-k ordering-critical) ----------------
// meanB[n] = (1/2048)[ sum_c mw[n,c]*(x[n]·Wsum1[:,c] + bs1[c]) + x[n]·wsum2 + cbsum ]
__global__ void rk_meanB(const float* __restrict__ x, const float* __restrict__ mw,
                         const double* __restrict__ Wsum1, const double* __restrict__ wsum2,
                         const double* __restrict__ bs1, const double* __restrict__ consts,
                         double* __restrict__ meanB) {
  const int n = blockIdx.x;
  const int t = threadIdx.x; // 0..63
  double acc[17];
#pragma unroll
  for (int j = 0; j < 17; ++j) acc[j] = 0.0;
#pragma unroll
  for (int rep = 0; rep < 4; ++rep) {
    const int i = t + rep * 64;
    const double xv = (double)x[n * 256 + i];
#pragma unroll
    for (int c = 0; c < 16; ++c) acc[c] += xv * Wsum1[i * 16 + c];
    acc[16] += xv * wsum2[i];
  }
  for (int off = 32; off > 0; off >>= 1) {
#pragma unroll
    for (int j = 0; j < 17; ++j) acc[j] += __shfl_down(acc[j], off, 64);
  }
  if (t == 0) {
    double s = acc[16] + consts[0];
#pragma unroll
    for (int c = 0; c < 16; ++c) s += (double)mw[n * 16 + c] * (acc[c] + bs1[c]);
    meanB[n] = s * (1.0 / 2048.0);
  }
}

// ---------------- generic f32 GEMM: C = act(A[M,256] * W[256,N] + bias) ----------
template<bool RELU, bool BIAS>
__global__ void rk_gemm(const float* __restrict__ A, const float* __restrict__ W,
                        const float* __restrict__ bias, float* __restrict__ C,
                        int M, int N) {
  __shared__ float As[64][68];  // transposed: As[k][row]
  __shared__ float Ws[64][68];  // Ws[k][col]
  const int t = threadIdx.x;
  const int n0 = blockIdx.x * 64;
  const int c0b = blockIdx.y * 64;
  const int tr = t & 15, tc = t >> 4;
  const int r0 = tr * 4, c0 = tc * 4;
  float acc[4][4] = {{0.f}};
  for (int kc = 0; kc < 256; kc += 64) {
    __syncthreads();
#pragma unroll
    for (int it = 0; it < 4; ++it) {
      const int idx = t + it * 256;
      const int rr = idx >> 4;
      const int cc = (idx & 15) * 4;
      const int gr = n0 + rr;
      float4 v = make_float4(0.f, 0.f, 0.f, 0.f);
      if (gr < M) v = *(const float4*)(A + (size_t)gr * 256 + kc + cc);
      As[cc + 0][rr] = v.x; As[cc + 1][rr] = v.y;
      As[cc + 2][rr] = v.z; As[cc + 3][rr] = v.w;
      *(float4*)&Ws[rr][cc] = *(const float4*)(W + (size_t)(kc + rr) * N + c0b + cc);
    }
    __syncthreads();
#pragma unroll
    for (int k = 0; k < 64; ++k) {
      const float4 a = *(const float4*)&As[k][r0];
      const float4 w = *(const float4*)&Ws[k][c0];
      acc[0][0] += a.x * w.x; acc[0][1] += a.x * w.y; acc[0][2] += a.x * w.z; acc[0][3] += a.x * w.w;
      acc[1][0] += a.y * w.x; acc[1][1] += a.y * w.y; acc[1][2] += a.y * w.z; acc[1][3] += a.y * w.w;
      acc[2][0] += a.z * w.x; acc[2][1] += a.z * w.y; acc[2][2] += a.z * w.z; acc[2][3] += a.z * w.w;
      acc[3][0] += a.w * w.x; acc[3][1] += a.w * w.y; acc[3][2] += a.w * w.z; acc[3][3] += a.w * w.w;
    }
  }
#pragma unroll
  for (int i = 0; i < 4; ++i) {
    const int gr = n0 + r0 + i;
    if (gr >= M) break;
    float4 v = make_float4(acc[i][0], acc[i][1], acc[i][2], acc[i][3]);
    if (BIAS) {
      v.x += bias[c0b + c0 + 0]; v.y += bias[c0b + c0 + 1];
      v.z += bias[c0b + c0 + 2]; v.w += bias[c0b + c0 + 3];
    }
    if (RELU) {
      v.x = fmaxf(v.x, 0.f); v.y = fmaxf(v.y, 0.f);
      v.z = fmaxf(v.z, 0.f); v.w = fmaxf(v.w, 0.f);
    }
    *(float4*)(C + (size_t)gr * N + c0b + c0) = v;
  }
}

// ---------------- K2b: GEMM vs Wg, fused contraction -> Bmat[n][l] ----------------
__global__ void rk_gemm_bmat(const float* __restrict__ A, const float* __restrict__ W,
                             const float* __restrict__ mw, const float* __restrict__ b_inc,
                             const float* __restrict__ C2, const float* __restrict__ cb,
                             float* __restrict__ Bmat, int M) {
  const int N = 1024;
  __shared__ float As[64][68];
  __shared__ float Ws[64][68];
  __shared__ float Cs[64][68];
  const int t = threadIdx.x;
  const int n0 = blockIdx.x * 64;
  const int c0b = blockIdx.y * 64;
  const int tr = t & 15, tc = t >> 4;
  const int r0 = tr * 4, c0 = tc * 4;
  float acc[4][4] = {{0.f}};
  for (int kc = 0; kc < 256; kc += 64) {
    __syncthreads();
#pragma unroll
    for (int it = 0; it < 4; ++it) {
      const int idx = t + it * 256;
      const int rr = idx >> 4;
      const int cc = (idx & 15) * 4;
      const int gr = n0 + rr;
      float4 v = make_float4(0.f, 0.f, 0.f, 0.f);
      if (gr < M) v = *(const float4*)(A + (size_t)gr * 256 + kc + cc);
      As[cc + 0][rr] = v.x; As[cc + 1][rr] = v.y;
      As[cc + 2][rr] = v.z; As[cc + 3][rr] = v.w;
      *(float4*)&Ws[rr][cc] = *(const float4*)(W + (size_t)(kc + rr) * N + c0b + cc);
    }
    __syncthreads();
#pragma unroll
    for (int k = 0; k < 64; ++k) {
      const float4 a = *(const float4*)&As[k][r0];
      const float4 w = *(const float4*)&Ws[k][c0];
      acc[0][0] += a.x * w.x; acc[0][1] += a.x * w.y; acc[0][2] += a.x * w.z; acc[0][3] += a.x * w.w;
      acc[1][0] += a.y * w.x; acc[1][1] += a.y * w.y; acc[1][2] += a.y * w.z; acc[1][3] += a.y * w.w;
      acc[2][0] += a.z * w.x; acc[2][1] += a.z * w.y; acc[2][2] += a.z * w.z; acc[2][3] += a.z * w.w;
      acc[3][0] += a.w * w.x; acc[3][1] += a.w * w.y; acc[3][2] += a.w * w.z; acc[3][3] += a.w * w.w;
    }
  }
#pragma unroll
  for (int i = 0; i < 4; ++i)
    *(float4*)&Cs[r0 + i][c0] = make_float4(acc[i][0], acc[i][1], acc[i][2], acc[i][3]);
  __syncthreads();
  const int n = t & 63;
  const int lq = t >> 6;                // 0..3
  const int gl = (c0b >> 4) + lq;       // global l
  const int gn = n0 + n;
  if (gn < M) {
    float s = 0.f;
#pragma unroll
    for (int c = 0; c < 16; ++c) s += mw[gn * 16 + c] * Cs[n][lq * 16 + c];
    s += C2[gn * 64 + gl];
    float sb = 0.f;
#pragma unroll
    for (int c = 0; c < 16; ++c) sb += mw[gn * 16 + c] * b_inc[gl * 32 + c];
    s += sb + cb[gl];
    Bmat[gn * 64 + gl] = s * (1.0f / 32.0f);
  }
}

// ---------------- K4: sortable keys + 16-bit-prefix histogram ----------------
__global__ void rk_keys(const int* __restrict__ ei, const float* __restrict__ ew,
                        const double* __restrict__ meanB,
                        unsigned long long* __restrict__ keys, unsigned* __restrict__ hist) {
  const int e = blockIdx.x * 256 + threadIdx.x;
  const int dst = ei[EE + e];
  const double aew = (double)ew[e] * meanB[dst];
  unsigned long long b = (unsigned long long)__double_as_longlong(aew);
  const unsigned long long s = (b & 0x8000000000000000ull) ? ~b : (b | 0x8000000000000000ull);
  keys[e] = s;
  atomicAdd(&hist[(unsigned)(s >> 48)], 1u);
}

// ---------------- K5: find boundary bin p, m = remaining in bin ----------------
__global__ void rk_select(const unsigned* __restrict__ hist, unsigned* __restrict__ meta) {
  __shared__ unsigned csum[1024];
  const int t = threadIdx.x;
  unsigned s = 0;
  for (int b = 0; b < 64; ++b) s += hist[t * 64 + b];
  csum[t] = s;
  __syncthreads();
  if (t == 0) {
    unsigned cum = 0;
    for (int c = 1023; c >= 0; --c) {
      if (cum + csum[c] >= KSEL) {
        for (int b = c * 64 + 63; b >= c * 64; --b) {
          const unsigned h = hist[b];
          if (cum + h >= KSEL) { meta[0] = (unsigned)b; meta[1] = KSEL - cum; return; }
          cum += h;
        }
      }
      cum += csum[c];
    }
    meta[0] = 0; meta[1] = KSEL - cum;
  }
}

// ---------------- K6: mark clear winners, collect boundary candidates ----------
__global__ void rk_mark(const unsigned long long* __restrict__ keys,
                        unsigned* __restrict__ meta, int* __restrict__ cand,
                        int* __restrict__ sel) {
  const int e = blockIdx.x * 256 + threadIdx.x;
  const unsigned p = meta[0];
  const unsigned s16 = (unsigned)(keys[e] >> 48);
  sel[e] = (s16 > p) ? 1 : 0;
  if (s16 == p) {
    const unsigned pos = atomicAdd(&meta[2], 1u);
    cand[pos] = e;
  }
}

// ---------------- K7: exact rank among boundary candidates ----------------
__global__ void rk_ties(const unsigned long long* __restrict__ keys,
                        const unsigned* __restrict__ meta, const int* __restrict__ cand,
                        int* __restrict__ sel) {
  const int C = (int)meta[2];
  const int m = (int)meta[1];
  for (int i = threadIdx.x; i < C; i += 256) {
    const int e_i = cand[i];
    const unsigned long long k_i = keys[e_i];
    int r = 0;
    for (int j = 0; j < C; ++j) {
      const int e_j = cand[j];
      const unsigned long long k_j = keys[e_j];
      if (k_j > k_i || (k_j == k_i && e_j < e_i)) ++r;
    }
    sel[e_i] = (r < m) ? 1 : 0;
  }
}

// ---------------- K8/K9/K10: segment softmax (64 cols) + scatter ----------------
__global__ void rk_smax(const int* __restrict__ ei, const float* __restrict__ ew,
                        const int* __restrict__ sel, const float* __restrict__ Bmat,
                        unsigned* __restrict__ Mmax) {
  const int t = threadIdx.x;
  const int e = blockIdx.x * 4 + (t >> 6);
  const int l = t & 63;
  if (!sel[e]) return;
  const int src = ei[e], dst = ei[EE + e];
  const float logit = Bmat[dst * 64 + l] * ew[e];
  atomicMax(&Mmax[src * 64 + l], encf(logit));
}

__global__ void rk_sden(const int* __restrict__ ei, const float* __restrict__ ew,
                        const int* __restrict__ sel, const float* __restrict__ Bmat,
                        const unsigned* __restrict__ Mmax, float* __restrict__ denom) {
  const int t = threadIdx.x;
  const int e = blockIdx.x * 4 + (t >> 6);
  const int l = t & 63;
  if (!sel[e]) return;
  const int src = ei[e], dst = ei[EE + e];
  const float logit = Bmat[dst * 64 + l] * ew[e];
  const float p = expf(logit - decf(Mmax[src * 64 + l]));
  unsafeAtomicAdd(&denom[src * 64 + l], p);
}

__global__ void rk_scatter(const int* __restrict__ ei, const float* __restrict__ ew,
                           const int* __restrict__ sel, const float* __restrict__ Bmat,
                           const unsigned* __restrict__ Mmax, const float* __restrict__ denom,
                           const float* __restrict__ V, float* __restrict__ out) {
  const int t = threadIdx.x;
  const int e = blockIdx.x * 4 + (t >> 6);
  const int l = t & 63;
  if (!sel[e]) return;
  const int src = ei[e], dst = ei[EE + e];
  const float logit = Bmat[dst * 64 + l] * ew[e];
  const float m = decf(Mmax[src * 64 + l]);
  const float w = expf(logit - m) / (denom[src * 64 + l] + 1e-16f);
  const float4 v = *(const float4*)(V + (size_t)dst * 256 + l * 4);
  unsafeAtomicAdd(&out[src * 256 + l * 4 + 0], v.x * w);
  unsafeAtomicAdd(&out[src * 256 + l * 4 + 1], v.y * w);
  unsafeAtomicAdd(&out[src * 256 + l * 4 + 2], v.z * w);
  unsafeAtomicAdd(&out[src * 256 + l * 4 + 3], v.w * w);
}

extern "C" void kernel_launch(void* const* d_in, const int* in_sizes, int n_in,
                              void* d_out, int out_size, void* d_ws, size_t ws_size,
                              hipStream_t stream) {
  const float* x       = (const float*)d_in[0];
  const float* p_t     = (const float*)d_in[1];
  const int*   ei      = (const int*)d_in[2];
  const float* ew      = (const float*)d_in[3];
  const float* W_value = (const float*)d_in[4];
  const float* b_value = (const float*)d_in[5];
  const float* W_inc   = (const float*)d_in[6];
  const float* b_inc   = (const float*)d_in[7];
  const float* mw      = (const float*)d_in[8];
  float* out = (float*)d_out;
  char* ws = (char*)d_ws;

  unsigned*           hist  = (unsigned*)(ws + O_HIST);
  unsigned*           meta  = (unsigned*)(ws + O_META);
  unsigned*           Mmax  = (unsigned*)(ws + O_MMAX);
  float*              den   = (float*)(ws + O_DEN);
  unsigned long long* keys  = (unsigned long long*)(ws + O_KEYS);
  int*                cand  = (int*)(ws + O_CAND);
  int*                sel   = (int*)(ws + O_SEL);
  double*             meanB = (double*)(ws + O_MEANB);
  float*              Bmat  = (float*)(ws + O_BMAT);
  float*              V     = (float*)(ws + O_V);
  float*              Wg    = (float*)(ws + O_WG);
  float*              P     = (float*)(ws + O_P);
  float*              C2    = (float*)(ws + O_C2);
  double*             Wsum1 = (double*)(ws + O_WSUM1);
  double*             wsum2 = (double*)(ws + O_WSUM2);
  double*             bs1   = (double*)(ws + O_BS1);
  float*              cb    = (float*)(ws + O_CB);
  double*             cst   = (double*)(ws + O_CONST);

  hipMemsetAsync(ws, 0, ZERO_BYTES, stream);
  hipMemsetAsync(d_out, 0, (size_t)out_size * sizeof(float), stream);

  rk_prep<<<256, 64, 0, stream>>>(W_inc, p_t, b_inc, Wg, P, Wsum1, wsum2, bs1, cb, cst);
  rk_meanB<<<NN, 64, 0, stream>>>(x, mw, Wsum1, wsum2, bs1, cst, meanB);
  rk_gemm<false, false><<<dim3(63, 1), 256, 0, stream>>>(x, P, nullptr, C2, NN, 64);
  rk_gemm<true, true><<<dim3(63, 4), 256, 0, stream>>>(x, W_value, b_value, V, NN, 256);
  rk_gemm_bmat<<<dim3(63, 16), 256, 0, stream>>>(x, Wg, mw, b_inc, C2, cb, Bmat, NN);
  rk_keys<<<250, 256, 0, stream>>>(ei, ew, meanB, keys, hist);
  rk_select<<<1, 1024, 0, stream>>>(hist, meta);
  rk_mark<<<250, 256, 0, stream>>>(keys, meta, cand, sel);
  rk_ties<<<1, 256, 0, stream>>>(keys, meta, cand, sel);
  rk_smax<<<16000, 256, 0, stream>>>(ei, ew, sel, Bmat, Mmax);
  rk_sden<<<16000, 256, 0, stream>>>(ei, ew, sel, Bmat, Mmax, den);
  rk_scatter<<<16000, 256, 0, stream>>>(ei, ew, sel, Bmat, Mmax, den, V, out);
}

// Round 2
// 220.881 us; speedup vs baseline: 1.4470x; 1.4470x over previous
//
#include <hip/hip_runtime.h>
#include <stdint.h>

// Problem constants
#define NN   4000      // nodes
#define EE   64000     // edges
#define KSEL 32000     // top-k
#define LL   64        // MAX_LEN
#define INCH 256       // IN_CH = OUT_CH

// ---------------- workspace layout (bytes) ----------------
static constexpr size_t O_HIST  = 0;                        // 65536 * 4
static constexpr size_t O_META  = O_HIST + 262144;          // 64 * 4
static constexpr size_t O_CNT   = O_META + 256;             // 4000*4 (pad 16384)
static constexpr size_t O_CNT2  = O_CNT + 16384;            // 4000*4 (pad 16384)
static constexpr size_t ZERO_BYTES = O_CNT2 + 16384;        // zeroed each call
static constexpr size_t O_OFFS  = ZERO_BYTES;               // 4000*4 (pad 16384)
static constexpr size_t O_BUCK  = O_OFFS + 16384;           // 32000*4
static constexpr size_t O_KEYS  = O_BUCK + 128000;          // 64000 * 8
static constexpr size_t O_CAND  = O_KEYS + 512000;          // 64000 * 4
static constexpr size_t O_SEL   = O_CAND + 256000;          // 64000 * 4
static constexpr size_t O_MEANB = O_SEL + 256000;           // 4000 * 8 (f64)
static constexpr size_t O_BMAT  = O_MEANB + 32000;          // 4000*64*4
static constexpr size_t O_V     = O_BMAT + 1024000;         // 4000*256*4
static constexpr size_t O_WG    = O_V + 4096000;            // 256*1024*4
static constexpr size_t O_P     = O_WG + 1048576;           // 256*64*4
static constexpr size_t O_C2    = O_P + 65536;              // 4000*64*4
static constexpr size_t O_WSUM1 = O_C2 + 1024000;           // 256*16*8 (f64)
static constexpr size_t O_WSUM2 = O_WSUM1 + 32768;          // 256*8 (f64)
static constexpr size_t O_BS1   = O_WSUM2 + 2048;           // 16*8 (f64)
static constexpr size_t O_CB    = O_BS1 + 128;              // 64*4
static constexpr size_t O_CONST = O_CB + 256;               // 8 (f64)

// ---------------- K0: weight precontractions ----------------
__global__ void rk_prep(const float* __restrict__ W_inc, const float* __restrict__ p_t,
                        const float* __restrict__ b_inc,
                        float* __restrict__ Wg, float* __restrict__ P,
                        double* __restrict__ Wsum1, double* __restrict__ wsum2,
                        double* __restrict__ bs1, float* __restrict__ cb,
                        double* __restrict__ consts) {
  const int i = blockIdx.x;   // 0..255
  const int l = threadIdx.x;  // 0..63
  __shared__ double sred[64];
  const int base = i * 2048 + l * 32;
#pragma unroll
  for (int c = 0; c < 16; ++c) Wg[i * 1024 + l * 16 + c] = W_inc[base + c];
  double accP = 0.0;
#pragma unroll
  for (int c = 0; c < 16; ++c)
    accP += (double)W_inc[base + 16 + c] * (double)p_t[l * 16 + c];
  P[i * 64 + l] = (float)accP;
  sred[l] = accP;
  __syncthreads();
  if (l == 0) {
    double s = 0.0;
    for (int j = 0; j < 64; ++j) s += sred[j];
    wsum2[i] = s;
  }
  if (l < 16) {
    double s = 0.0;
    for (int l2 = 0; l2 < 64; ++l2) s += (double)W_inc[i * 2048 + l2 * 32 + l];
    Wsum1[i * 16 + l] = s;
  }
  if (i == 0) {
    __syncthreads();
    if (l < 16) {
      double s = 0.0;
      for (int l2 = 0; l2 < 64; ++l2) s += (double)b_inc[l2 * 32 + l];
      bs1[l] = s;
    }
    double cbv = 0.0;
#pragma unroll
    for (int c = 0; c < 16; ++c)
      cbv += (double)p_t[l * 16 + c] * (double)b_inc[l * 32 + 16 + c];
    cb[l] = (float)cbv;
    sred[l] = cbv;
    __syncthreads();
    if (l == 0) {
      double s = 0.0;
      for (int j = 0; j < 64; ++j) s += sred[j];
      consts[0] = s;
    }
  }
}

// ---------------- K1: meanB[n] in f64 (top-k ordering-critical) ----------------
__global__ void rk_meanB(const float* __restrict__ x, const float* __restrict__ mw,
                         const double* __restrict__ Wsum1, const double* __restrict__ wsum2,
                         const double* __restrict__ bs1, const double* __restrict__ consts,
                         double* __restrict__ meanB) {
  const int n = blockIdx.x;
  const int t = threadIdx.x; // 0..63
  double acc[17];
#pragma unroll
  for (int j = 0; j < 17; ++j) acc[j] = 0.0;
#pragma unroll
  for (int rep = 0; rep < 4; ++rep) {
    const int i = t + rep * 64;
    const double xv = (double)x[n * 256 + i];
#pragma unroll
    for (int c = 0; c < 16; ++c) acc[c] += xv * Wsum1[i * 16 + c];
    acc[16] += xv * wsum2[i];
  }
  for (int off = 32; off > 0; off >>= 1) {
#pragma unroll
    for (int j = 0; j < 17; ++j) acc[j] += __shfl_down(acc[j], off, 64);
  }
  if (t == 0) {
    double s = acc[16] + consts[0];
#pragma unroll
    for (int c = 0; c < 16; ++c) s += (double)mw[n * 16 + c] * (acc[c] + bs1[c]);
    meanB[n] = s * (1.0 / 2048.0);
  }
}

// ---------------- generic f32 GEMM: C = act(A[M,256] * W[256,N] + bias) ----------
template<bool RELU, bool BIAS>
__global__ void rk_gemm(const float* __restrict__ A, const float* __restrict__ W,
                        const float* __restrict__ bias, float* __restrict__ C,
                        int M, int N) {
  __shared__ float As[64][68];  // transposed: As[k][row]
  __shared__ float Ws[64][68];  // Ws[k][col]
  const int t = threadIdx.x;
  const int n0 = blockIdx.x * 64;
  const int c0b = blockIdx.y * 64;
  const int tr = t & 15, tc = t >> 4;
  const int r0 = tr * 4, c0 = tc * 4;
  float acc[4][4] = {{0.f}};
  for (int kc = 0; kc < 256; kc += 64) {
    __syncthreads();
#pragma unroll
    for (int it = 0; it < 4; ++it) {
      const int idx = t + it * 256;
      const int rr = idx >> 4;
      const int cc = (idx & 15) * 4;
      const int gr = n0 + rr;
      float4 v = make_float4(0.f, 0.f, 0.f, 0.f);
      if (gr < M) v = *(const float4*)(A + (size_t)gr * 256 + kc + cc);
      As[cc + 0][rr] = v.x; As[cc + 1][rr] = v.y;
      As[cc + 2][rr] = v.z; As[cc + 3][rr] = v.w;
      *(float4*)&Ws[rr][cc] = *(const float4*)(W + (size_t)(kc + rr) * N + c0b + cc);
    }
    __syncthreads();
#pragma unroll
    for (int k = 0; k < 64; ++k) {
      const float4 a = *(const float4*)&As[k][r0];
      const float4 w = *(const float4*)&Ws[k][c0];
      acc[0][0] += a.x * w.x; acc[0][1] += a.x * w.y; acc[0][2] += a.x * w.z; acc[0][3] += a.x * w.w;
      acc[1][0] += a.y * w.x; acc[1][1] += a.y * w.y; acc[1][2] += a.y * w.z; acc[1][3] += a.y * w.w;
      acc[2][0] += a.z * w.x; acc[2][1] += a.z * w.y; acc[2][2] += a.z * w.z; acc[2][3] += a.z * w.w;
      acc[3][0] += a.w * w.x; acc[3][1] += a.w * w.y; acc[3][2] += a.w * w.z; acc[3][3] += a.w * w.w;
    }
  }
#pragma unroll
  for (int i = 0; i < 4; ++i) {
    const int gr = n0 + r0 + i;
    if (gr >= M) break;
    float4 v = make_float4(acc[i][0], acc[i][1], acc[i][2], acc[i][3]);
    if (BIAS) {
      v.x += bias[c0b + c0 + 0]; v.y += bias[c0b + c0 + 1];
      v.z += bias[c0b + c0 + 2]; v.w += bias[c0b + c0 + 3];
    }
    if (RELU) {
      v.x = fmaxf(v.x, 0.f); v.y = fmaxf(v.y, 0.f);
      v.z = fmaxf(v.z, 0.f); v.w = fmaxf(v.w, 0.f);
    }
    *(float4*)(C + (size_t)gr * N + c0b + c0) = v;
  }
}

// ---------------- K2b: GEMM vs Wg, fused contraction -> Bmat[n][l] ----------------
__global__ void rk_gemm_bmat(const float* __restrict__ A, const float* __restrict__ W,
                             const float* __restrict__ mw, const float* __restrict__ b_inc,
                             const float* __restrict__ C2, const float* __restrict__ cb,
                             float* __restrict__ Bmat, int M) {
  const int N = 1024;
  __shared__ float As[64][68];
  __shared__ float Ws[64][68];
  __shared__ float Cs[64][68];
  const int t = threadIdx.x;
  const int n0 = blockIdx.x * 64;
  const int c0b = blockIdx.y * 64;
  const int tr = t & 15, tc = t >> 4;
  const int r0 = tr * 4, c0 = tc * 4;
  float acc[4][4] = {{0.f}};
  for (int kc = 0; kc < 256; kc += 64) {
    __syncthreads();
#pragma unroll
    for (int it = 0; it < 4; ++it) {
      const int idx = t + it * 256;
      const int rr = idx >> 4;
      const int cc = (idx & 15) * 4;
      const int gr = n0 + rr;
      float4 v = make_float4(0.f, 0.f, 0.f, 0.f);
      if (gr < M) v = *(const float4*)(A + (size_t)gr * 256 + kc + cc);
      As[cc + 0][rr] = v.x; As[cc + 1][rr] = v.y;
      As[cc + 2][rr] = v.z; As[cc + 3][rr] = v.w;
      *(float4*)&Ws[rr][cc] = *(const float4*)(W + (size_t)(kc + rr) * N + c0b + cc);
    }
    __syncthreads();
#pragma unroll
    for (int k = 0; k < 64; ++k) {
      const float4 a = *(const float4*)&As[k][r0];
      const float4 w = *(const float4*)&Ws[k][c0];
      acc[0][0] += a.x * w.x; acc[0][1] += a.x * w.y; acc[0][2] += a.x * w.z; acc[0][3] += a.x * w.w;
      acc[1][0] += a.y * w.x; acc[1][1] += a.y * w.y; acc[1][2] += a.y * w.z; acc[1][3] += a.y * w.w;
      acc[2][0] += a.z * w.x; acc[2][1] += a.z * w.y; acc[2][2] += a.z * w.z; acc[2][3] += a.z * w.w;
      acc[3][0] += a.w * w.x; acc[3][1] += a.w * w.y; acc[3][2] += a.w * w.z; acc[3][3] += a.w * w.w;
    }
  }
#pragma unroll
  for (int i = 0; i < 4; ++i)
    *(float4*)&Cs[r0 + i][c0] = make_float4(acc[i][0], acc[i][1], acc[i][2], acc[i][3]);
  __syncthreads();
  const int n = t & 63;
  const int lq = t >> 6;                // 0..3
  const int gl = (c0b >> 4) + lq;       // global l
  const int gn = n0 + n;
  if (gn < M) {
    float s = 0.f;
#pragma unroll
    for (int c = 0; c < 16; ++c) s += mw[gn * 16 + c] * Cs[n][lq * 16 + c];
    s += C2[gn * 64 + gl];
    float sb = 0.f;
#pragma unroll
    for (int c = 0; c < 16; ++c) sb += mw[gn * 16 + c] * b_inc[gl * 32 + c];
    s += sb + cb[gl];
    Bmat[gn * 64 + gl] = s * (1.0f / 32.0f);
  }
}

// ---------------- K4: sortable keys + 16-bit-prefix histogram ----------------
__global__ void rk_keys(const int* __restrict__ ei, const float* __restrict__ ew,
                        const double* __restrict__ meanB,
                        unsigned long long* __restrict__ keys, unsigned* __restrict__ hist) {
  const int e = blockIdx.x * 256 + threadIdx.x;
  const int dst = ei[EE + e];
  const double aew = (double)ew[e] * meanB[dst];
  unsigned long long b = (unsigned long long)__double_as_longlong(aew);
  const unsigned long long s = (b & 0x8000000000000000ull) ? ~b : (b | 0x8000000000000000ull);
  keys[e] = s;
  atomicAdd(&hist[(unsigned)(s >> 48)], 1u);
}

// ---------------- K5: find boundary bin p, m = remaining in bin ----------------
__global__ void rk_select(const unsigned* __restrict__ hist, unsigned* __restrict__ meta) {
  __shared__ unsigned csum[1024];
  const int t = threadIdx.x;
  unsigned s = 0;
  for (int b = 0; b < 64; ++b) s += hist[t * 64 + b];
  csum[t] = s;
  __syncthreads();
  if (t == 0) {
    unsigned cum = 0;
    for (int c = 1023; c >= 0; --c) {
      if (cum + csum[c] >= KSEL) {
        for (int b = c * 64 + 63; b >= c * 64; --b) {
          const unsigned h = hist[b];
          if (cum + h >= KSEL) { meta[0] = (unsigned)b; meta[1] = KSEL - cum; return; }
          cum += h;
        }
      }
      cum += csum[c];
    }
    meta[0] = 0; meta[1] = KSEL - cum;
  }
}

// ---------------- K6: mark clear winners, collect boundary candidates ----------
__global__ void rk_mark(const unsigned long long* __restrict__ keys,
                        unsigned* __restrict__ meta, int* __restrict__ cand,
                        int* __restrict__ sel) {
  const int e = blockIdx.x * 256 + threadIdx.x;
  const unsigned p = meta[0];
  const unsigned s16 = (unsigned)(keys[e] >> 48);
  sel[e] = (s16 > p) ? 1 : 0;
  if (s16 == p) {
    const unsigned pos = atomicAdd(&meta[2], 1u);
    cand[pos] = e;
  }
}

// ---------------- K7: exact rank among boundary candidates ----------------
__global__ void rk_ties(const unsigned long long* __restrict__ keys,
                        const unsigned* __restrict__ meta, const int* __restrict__ cand,
                        int* __restrict__ sel) {
  const int C = (int)meta[2];
  const int m = (int)meta[1];
  for (int i = threadIdx.x; i < C; i += 256) {
    const int e_i = cand[i];
    const unsigned long long k_i = keys[e_i];
    int r = 0;
    for (int j = 0; j < C; ++j) {
      const int e_j = cand[j];
      const unsigned long long k_j = keys[e_j];
      if (k_j > k_i || (k_j == k_i && e_j < e_i)) ++r;
    }
    sel[e_i] = (r < m) ? 1 : 0;
  }
}

// ---------------- K8: CSR build — count selected edges per src ----------------
__global__ void rk_count(const int* __restrict__ ei, const int* __restrict__ sel,
                         unsigned* __restrict__ cnt) {
  const int e = blockIdx.x * 256 + threadIdx.x;
  if (sel[e]) atomicAdd(&cnt[ei[e]], 1u);
}

// ---------------- K9: exclusive scan over 4000 counts (single block) ----------
__global__ void rk_scan(const unsigned* __restrict__ cnt, unsigned* __restrict__ offs) {
  __shared__ unsigned part[1024];
  const int t = threadIdx.x;
  unsigned v[4];
  unsigned s = 0;
#pragma unroll
  for (int j = 0; j < 4; ++j) {
    const int i = t * 4 + j;
    v[j] = (i < NN) ? cnt[i] : 0u;
    s += v[j];
  }
  part[t] = s;
  __syncthreads();
  for (int off = 1; off < 1024; off <<= 1) {
    const unsigned a = (t >= off) ? part[t - off] : 0u;
    __syncthreads();
    part[t] += a;
    __syncthreads();
  }
  unsigned ex = (t > 0) ? part[t - 1] : 0u;
#pragma unroll
  for (int j = 0; j < 4; ++j) {
    const int i = t * 4 + j;
    if (i < NN) { offs[i] = ex; ex += v[j]; }
  }
}

// ---------------- K10: fill CSR buckets ----------------
__global__ void rk_fill(const int* __restrict__ ei, const int* __restrict__ sel,
                        const unsigned* __restrict__ offs, unsigned* __restrict__ cnt2,
                        int* __restrict__ bucket) {
  const int e = blockIdx.x * 256 + threadIdx.x;
  if (sel[e]) {
    const int src = ei[e];
    const unsigned pos = offs[src] + atomicAdd(&cnt2[src], 1u);
    bucket[pos] = e;
  }
}

// ---------------- K11: per-node gather softmax + weighted V accumulate -------
__global__ void rk_out(const int* __restrict__ ei, const float* __restrict__ ew,
                       const unsigned* __restrict__ offs, const unsigned* __restrict__ cnt,
                       const int* __restrict__ bucket, const float* __restrict__ Bmat,
                       const float* __restrict__ V, float* __restrict__ out) {
  const int n = blockIdx.x;
  const int t = threadIdx.x;      // 0..255
  const int l = t >> 2;           // 0..63
  const unsigned o0 = offs[n];
  const unsigned d = cnt[n];
  float m = -1e30f;
  for (unsigned i = 0; i < d; ++i) {
    const int e = bucket[o0 + i];
    const float logit = Bmat[ei[EE + e] * 64 + l] * ew[e];
    m = fmaxf(m, logit);
  }
  float s = 0.f, acc = 0.f;
  for (unsigned i = 0; i < d; ++i) {
    const int e = bucket[o0 + i];
    const int dst = ei[EE + e];
    const float p = expf(Bmat[dst * 64 + l] * ew[e] - m);
    s += p;
    acc += p * V[(size_t)dst * 256 + t];
  }
  out[(size_t)n * 256 + t] = acc / (s + 1e-16f);
}

extern "C" void kernel_launch(void* const* d_in, const int* in_sizes, int n_in,
                              void* d_out, int out_size, void* d_ws, size_t ws_size,
                              hipStream_t stream) {
  const float* x       = (const float*)d_in[0];
  const float* p_t     = (const float*)d_in[1];
  const int*   ei      = (const int*)d_in[2];
  const float* ew      = (const float*)d_in[3];
  const float* W_value = (const float*)d_in[4];
  const float* b_value = (const float*)d_in[5];
  const float* W_inc   = (const float*)d_in[6];
  const float* b_inc   = (const float*)d_in[7];
  const float* mw      = (const float*)d_in[8];
  float* out = (float*)d_out;
  char* ws = (char*)d_ws;

  unsigned*           hist  = (unsigned*)(ws + O_HIST);
  unsigned*           meta  = (unsigned*)(ws + O_META);
  unsigned*           cnt   = (unsigned*)(ws + O_CNT);
  unsigned*           cnt2  = (unsigned*)(ws + O_CNT2);
  unsigned*           offs  = (unsigned*)(ws + O_OFFS);
  int*                buck  = (int*)(ws + O_BUCK);
  unsigned long long* keys  = (unsigned long long*)(ws + O_KEYS);
  int*                cand  = (int*)(ws + O_CAND);
  int*                sel   = (int*)(ws + O_SEL);
  double*             meanB = (double*)(ws + O_MEANB);
  float*              Bmat  = (float*)(ws + O_BMAT);
  float*              V     = (float*)(ws + O_V);
  float*              Wg    = (float*)(ws + O_WG);
  float*              P     = (float*)(ws + O_P);
  float*              C2    = (float*)(ws + O_C2);
  double*             Wsum1 = (double*)(ws + O_WSUM1);
  double*             wsum2 = (double*)(ws + O_WSUM2);
  double*             bs1   = (double*)(ws + O_BS1);
  float*              cb    = (float*)(ws + O_CB);
  double*             cst   = (double*)(ws + O_CONST);

  hipMemsetAsync(ws, 0, ZERO_BYTES, stream);

  rk_prep<<<256, 64, 0, stream>>>(W_inc, p_t, b_inc, Wg, P, Wsum1, wsum2, bs1, cb, cst);
  rk_meanB<<<NN, 64, 0, stream>>>(x, mw, Wsum1, wsum2, bs1, cst, meanB);
  rk_gemm<false, false><<<dim3(63, 1), 256, 0, stream>>>(x, P, nullptr, C2, NN, 64);
  rk_gemm<true, true><<<dim3(63, 4), 256, 0, stream>>>(x, W_value, b_value, V, NN, 256);
  rk_gemm_bmat<<<dim3(63, 16), 256, 0, stream>>>(x, Wg, mw, b_inc, C2, cb, Bmat, NN);
  rk_keys<<<250, 256, 0, stream>>>(ei, ew, meanB, keys, hist);
  rk_select<<<1, 1024, 0, stream>>>(hist, meta);
  rk_mark<<<250, 256, 0, stream>>>(keys, meta, cand, sel);
  rk_ties<<<1, 256, 0, stream>>>(keys, meta, cand, sel);
  rk_count<<<250, 256, 0, stream>>>(ei, sel, cnt);
  rk_scan<<<1, 1024, 0, stream>>>(cnt, offs);
  rk_fill<<<250, 256, 0, stream>>>(ei, sel, offs, cnt2, buck);
  rk_out<<<NN, 256, 0, stream>>>(ei, ew, offs, cnt, buck, Bmat, V, out);
}

// Round 3
// 175.109 us; speedup vs baseline: 1.8252x; 1.2614x over previous
//
#include <hip/hip_runtime.h>
#include <stdint.h>

// Problem constants
#define NN   4000      // nodes
#define EE   64000     // edges
#define KSEL 32000     // top-k
#define LL   64        // MAX_LEN
#define INCH 256       // IN_CH = OUT_CH

typedef __attribute__((ext_vector_type(8))) short bf16x8;
typedef __attribute__((ext_vector_type(4))) float f32x4;

// ---------------- workspace layout (bytes) ----------------
static constexpr size_t O_HIST  = 0;                        // 65536 * 4
static constexpr size_t O_META  = 262144;                   // 64 * 4
static constexpr size_t O_CNT   = 262400;                   // 4000*4 (pad 16384)
static constexpr size_t O_CNT2  = 278784;                   // 4000*4 (pad 16384)
static constexpr size_t ZERO_BYTES = 295168;                // zeroed each call
static constexpr size_t O_OFFS  = 295168;                   // 16384
static constexpr size_t O_BUCK  = 311552;                   // 32000*4
static constexpr size_t O_KEYS  = 439552;                   // 64000*8
static constexpr size_t O_CAND  = 951552;                   // 64000*4
static constexpr size_t O_SEL   = 1207552;                  // 64000*4
static constexpr size_t O_MEANB = 1463552;                  // 4000*8 (f64)
static constexpr size_t O_BMAT  = 1495552;                  // 4000*64*4
static constexpr size_t O_V     = 2519552;                  // 4000*256*2 (bf16)
static constexpr size_t O_XB    = 4567552;                  // 4000*256*2 (bf16)
static constexpr size_t O_WALLT = 6615552;                  // 1088*256*2 (bf16, transposed)
static constexpr size_t O_WVT   = 7172608;                  // 256*256*2 (bf16, transposed)
static constexpr size_t O_WSUM1 = 7303680;                  // 256*16*8 (f64)
static constexpr size_t O_WSUM2 = 7336448;                  // 256*8 (f64)
static constexpr size_t O_BS1   = 7338496;                  // 16*8 (f64)
static constexpr size_t O_CB    = 7338624;                  // 64*4
static constexpr size_t O_CONST = 7338880;                  // 8 (f64)

__device__ __forceinline__ unsigned short f2b(float f) {  // f32 -> bf16 (RNE)
  union { float f; unsigned u; } v; v.f = f;
  const unsigned r = v.u + 0x7fffu + ((v.u >> 16) & 1u);
  return (unsigned short)(r >> 16);
}
__device__ __forceinline__ float b2f(unsigned short b) {
  return __uint_as_float(((unsigned)b) << 16);
}

// ---------------- K0: weight precontractions + bf16 transposed weights --------
// Wallt[col][k] (bf16): col 0..1023 = Wg col (l*16+c), col 1024..1087 = P col l
// Wvt[n][k] (bf16) = W_value[k][n]
// Wsum1/wsum2/bs1/consts: f64 exact path for top-k;  cb[l] f32 for Bmat bias
__global__ void rk_prep(const float* __restrict__ W_inc, const float* __restrict__ p_t,
                        const float* __restrict__ b_inc, const float* __restrict__ W_value,
                        unsigned short* __restrict__ Wallt, unsigned short* __restrict__ Wvt,
                        double* __restrict__ Wsum1, double* __restrict__ wsum2,
                        double* __restrict__ bs1, float* __restrict__ cb,
                        double* __restrict__ consts) {
  const int i = blockIdx.x;   // 0..255 (k index)
  const int l = threadIdx.x;  // 0..63
  __shared__ double sred[64];
  const int base = i * 2048 + l * 32;
#pragma unroll
  for (int c = 0; c < 16; ++c)
    Wallt[(size_t)(l * 16 + c) * 256 + i] = f2b(W_inc[base + c]);
  double accP = 0.0;
#pragma unroll
  for (int c = 0; c < 16; ++c)
    accP += (double)W_inc[base + 16 + c] * (double)p_t[l * 16 + c];
  Wallt[(size_t)(1024 + l) * 256 + i] = f2b((float)accP);
#pragma unroll
  for (int j = 0; j < 4; ++j)
    Wvt[(size_t)(l * 4 + j) * 256 + i] = f2b(W_value[i * 256 + l * 4 + j]);
  sred[l] = accP;
  __syncthreads();
  if (l == 0) {
    double s = 0.0;
    for (int j = 0; j < 64; ++j) s += sred[j];
    wsum2[i] = s;
  }
  if (l < 16) {
    double s = 0.0;
    for (int l2 = 0; l2 < 64; ++l2) s += (double)W_inc[i * 2048 + l2 * 32 + l];
    Wsum1[i * 16 + l] = s;
  }
  if (i == 0) {
    __syncthreads();
    if (l < 16) {
      double s = 0.0;
      for (int l2 = 0; l2 < 64; ++l2) s += (double)b_inc[l2 * 32 + l];
      bs1[l] = s;
    }
    double cbv = 0.0;
#pragma unroll
    for (int c = 0; c < 16; ++c)
      cbv += (double)p_t[l * 16 + c] * (double)b_inc[l * 32 + 16 + c];
    cb[l] = (float)cbv;
    sred[l] = cbv;
    __syncthreads();
    if (l == 0) {
      double s = 0.0;
      for (int j = 0; j < 64; ++j) s += sred[j];
      consts[0] = s;
    }
  }
}

// ---------------- K1: meanB[n] in f64 (top-k ordering-critical) + x->bf16 ----
__global__ void rk_meanB(const float* __restrict__ x, const float* __restrict__ mw,
                         const double* __restrict__ Wsum1, const double* __restrict__ wsum2,
                         const double* __restrict__ bs1, const double* __restrict__ consts,
                         double* __restrict__ meanB, unsigned short* __restrict__ xb) {
  const int n = blockIdx.x;
  const int t = threadIdx.x; // 0..63
  double acc[17];
#pragma unroll
  for (int j = 0; j < 17; ++j) acc[j] = 0.0;
#pragma unroll
  for (int rep = 0; rep < 4; ++rep) {
    const int i = t + rep * 64;
    const float xv_f = x[n * 256 + i];
    xb[(size_t)n * 256 + i] = f2b(xv_f);
    const double xv = (double)xv_f;
#pragma unroll
    for (int c = 0; c < 16; ++c) acc[c] += xv * Wsum1[i * 16 + c];
    acc[16] += xv * wsum2[i];
  }
  for (int off = 32; off > 0; off >>= 1) {
#pragma unroll
    for (int j = 0; j < 17; ++j) acc[j] += __shfl_down(acc[j], off, 64);
  }
  if (t == 0) {
    double s = acc[16] + consts[0];
#pragma unroll
    for (int c = 0; c < 16; ++c) s += (double)mw[n * 16 + c] * (acc[c] + bs1[c]);
    meanB[n] = s * (1.0 / 2048.0);
  }
}

// ---------------- K2: MFMA Bmat kernel -------------------------------------
// Per block: 32 rows x 16 l's.  Wave w: 4 l's (4 Wg tiles) + C2 tile (redundant).
// Bmat[n][l] = (1/32)( sum_c mw[n,c]*(G[n,l,c]+b_inc[l*32+c]) + C2[n,l] + cb[l] )
__global__ __launch_bounds__(256) void rk_bmat(
    const unsigned short* __restrict__ xb, const unsigned short* __restrict__ Wallt,
    const float* __restrict__ mw, const float* __restrict__ b_inc,
    const float* __restrict__ cb, float* __restrict__ Bmat) {
  const int t = threadIdx.x;
  const int wv = t >> 6, lane = t & 63;
  const int lr = lane & 15, kg = lane >> 4;
  const int n0 = blockIdx.x * 32;
  const int l0 = blockIdx.y * 16;
  f32x4 acc[2][5] = {};
  const unsigned short* ap0 = xb + (size_t)(n0 + lr) * 256 + kg * 8;
  const unsigned short* ap1 = ap0 + 16 * 256;
  const unsigned short* bp[5];
#pragma unroll
  for (int j = 0; j < 4; ++j)
    bp[j] = Wallt + (size_t)((l0 + wv * 4 + j) * 16 + lr) * 256 + kg * 8;
  bp[4] = Wallt + (size_t)(1024 + l0 + lr) * 256 + kg * 8;
#pragma unroll
  for (int kk = 0; kk < 8; ++kk) {
    const bf16x8 a0 = *(const bf16x8*)(ap0 + kk * 32);
    const bf16x8 a1 = *(const bf16x8*)(ap1 + kk * 32);
#pragma unroll
    for (int j = 0; j < 5; ++j) {
      const bf16x8 b = *(const bf16x8*)(bp[j] + kk * 32);
      acc[0][j] = __builtin_amdgcn_mfma_f32_16x16x32_bf16(a0, b, acc[0][j], 0, 0, 0);
      acc[1][j] = __builtin_amdgcn_mfma_f32_16x16x32_bf16(a1, b, acc[1][j], 0, 0, 0);
    }
  }
  // D layout: col = lane&15, row = (lane>>4)*4 + reg
  const int c = lr, rg = kg;
#pragma unroll
  for (int rt = 0; rt < 2; ++rt) {
    const int rbase = n0 + rt * 16 + rg * 4;
    float mwv[4];
#pragma unroll
    for (int r = 0; r < 4; ++r) mwv[r] = mw[(rbase + r) * 16 + c];
#pragma unroll
    for (int j = 0; j < 4; ++j) {
      const int lj = l0 + wv * 4 + j;
      const float bi = b_inc[lj * 32 + c];
      const float cbl = cb[lj];
#pragma unroll
      for (int r = 0; r < 4; ++r) {
        float prod = (acc[rt][j][r] + bi) * mwv[r];
#pragma unroll
        for (int off = 1; off < 16; off <<= 1) prod += __shfl_xor(prod, off, 64);
        const float c2 = __shfl(acc[rt][4][r], (lane & 48) | (wv * 4 + j), 64);
        if (c == 0) Bmat[(rbase + r) * 64 + lj] = (prod + c2 + cbl) * (1.0f / 32.0f);
      }
    }
  }
}

// ---------------- K3: MFMA V kernel: V = relu(x @ W_value + b) (bf16 out) ----
__global__ __launch_bounds__(256) void rk_v(
    const unsigned short* __restrict__ xb, const unsigned short* __restrict__ Wvt,
    const float* __restrict__ b_value, unsigned short* __restrict__ V) {
  const int t = threadIdx.x;
  const int wv = t >> 6, lane = t & 63;
  const int lr = lane & 15, kg = lane >> 4;
  const int n0 = blockIdx.x * 32;
  const int c0 = blockIdx.y * 64 + wv * 16;
  f32x4 acc[2] = {};
  const unsigned short* ap0 = xb + (size_t)(n0 + lr) * 256 + kg * 8;
  const unsigned short* ap1 = ap0 + 16 * 256;
  const unsigned short* bp = Wvt + (size_t)(c0 + lr) * 256 + kg * 8;
#pragma unroll
  for (int kk = 0; kk < 8; ++kk) {
    const bf16x8 a0 = *(const bf16x8*)(ap0 + kk * 32);
    const bf16x8 a1 = *(const bf16x8*)(ap1 + kk * 32);
    const bf16x8 b = *(const bf16x8*)(bp + kk * 32);
    acc[0] = __builtin_amdgcn_mfma_f32_16x16x32_bf16(a0, b, acc[0], 0, 0, 0);
    acc[1] = __builtin_amdgcn_mfma_f32_16x16x32_bf16(a1, b, acc[1], 0, 0, 0);
  }
  const int c = lr, rg = kg;
  const float bv = b_value[c0 + c];
#pragma unroll
  for (int rt = 0; rt < 2; ++rt)
#pragma unroll
    for (int r = 0; r < 4; ++r) {
      const float val = fmaxf(acc[rt][r] + bv, 0.f);
      V[(size_t)(n0 + rt * 16 + rg * 4 + r) * 256 + c0 + c] = f2b(val);
    }
}

// ---------------- K4: sortable keys + 16-bit-prefix histogram ----------------
__global__ void rk_keys(const int* __restrict__ ei, const float* __restrict__ ew,
                        const double* __restrict__ meanB,
                        unsigned long long* __restrict__ keys, unsigned* __restrict__ hist) {
  const int e = blockIdx.x * 256 + threadIdx.x;
  const int dst = ei[EE + e];
  const double aew = (double)ew[e] * meanB[dst];
  unsigned long long b = (unsigned long long)__double_as_longlong(aew);
  const unsigned long long s = (b & 0x8000000000000000ull) ? ~b : (b | 0x8000000000000000ull);
  keys[e] = s;
  atomicAdd(&hist[(unsigned)(s >> 48)], 1u);
}

// ---------------- K5: find boundary bin p, m = remaining in bin ----------------
__global__ void rk_select(const unsigned* __restrict__ hist, unsigned* __restrict__ meta) {
  __shared__ unsigned csum[1024];
  const int t = threadIdx.x;
  unsigned s = 0;
  for (int b = 0; b < 64; ++b) s += hist[t * 64 + b];
  csum[t] = s;
  __syncthreads();
  if (t == 0) {
    unsigned cum = 0;
    for (int c = 1023; c >= 0; --c) {
      if (cum + csum[c] >= KSEL) {
        for (int b = c * 64 + 63; b >= c * 64; --b) {
          const unsigned h = hist[b];
          if (cum + h >= KSEL) { meta[0] = (unsigned)b; meta[1] = KSEL - cum; return; }
          cum += h;
        }
      }
      cum += csum[c];
    }
    meta[0] = 0; meta[1] = KSEL - cum;
  }
}

// ---------------- K6: mark clear winners, collect boundary candidates ----------
__global__ void rk_mark(const unsigned long long* __restrict__ keys,
                        unsigned* __restrict__ meta, int* __restrict__ cand,
                        int* __restrict__ sel) {
  const int e = blockIdx.x * 256 + threadIdx.x;
  const unsigned p = meta[0];
  const unsigned s16 = (unsigned)(keys[e] >> 48);
  sel[e] = (s16 > p) ? 1 : 0;
  if (s16 == p) {
    const unsigned pos = atomicAdd(&meta[2], 1u);
    cand[pos] = e;
  }
}

// ---------------- K7: exact rank among boundary candidates ----------------
__global__ void rk_ties(const unsigned long long* __restrict__ keys,
                        const unsigned* __restrict__ meta, const int* __restrict__ cand,
                        int* __restrict__ sel) {
  const int C = (int)meta[2];
  const int m = (int)meta[1];
  for (int i = threadIdx.x; i < C; i += 256) {
    const int e_i = cand[i];
    const unsigned long long k_i = keys[e_i];
    int r = 0;
    for (int j = 0; j < C; ++j) {
      const int e_j = cand[j];
      const unsigned long long k_j = keys[e_j];
      if (k_j > k_i || (k_j == k_i && e_j < e_i)) ++r;
    }
    sel[e_i] = (r < m) ? 1 : 0;
  }
}

// ---------------- K8: CSR build — count selected edges per src ----------------
__global__ void rk_count(const int* __restrict__ ei, const int* __restrict__ sel,
                         unsigned* __restrict__ cnt) {
  const int e = blockIdx.x * 256 + threadIdx.x;
  if (sel[e]) atomicAdd(&cnt[ei[e]], 1u);
}

// ---------------- K9: exclusive scan over 4000 counts (single block) ----------
__global__ void rk_scan(const unsigned* __restrict__ cnt, unsigned* __restrict__ offs) {
  __shared__ unsigned part[1024];
  const int t = threadIdx.x;
  unsigned v[4];
  unsigned s = 0;
#pragma unroll
  for (int j = 0; j < 4; ++j) {
    const int i = t * 4 + j;
    v[j] = (i < NN) ? cnt[i] : 0u;
    s += v[j];
  }
  part[t] = s;
  __syncthreads();
  for (int off = 1; off < 1024; off <<= 1) {
    const unsigned a = (t >= off) ? part[t - off] : 0u;
    __syncthreads();
    part[t] += a;
    __syncthreads();
  }
  unsigned ex = (t > 0) ? part[t - 1] : 0u;
#pragma unroll
  for (int j = 0; j < 4; ++j) {
    const int i = t * 4 + j;
    if (i < NN) { offs[i] = ex; ex += v[j]; }
  }
}

// ---------------- K10: fill CSR buckets ----------------
__global__ void rk_fill(const int* __restrict__ ei, const int* __restrict__ sel,
                        const unsigned* __restrict__ offs, unsigned* __restrict__ cnt2,
                        int* __restrict__ bucket) {
  const int e = blockIdx.x * 256 + threadIdx.x;
  if (sel[e]) {
    const int src = ei[e];
    const unsigned pos = offs[src] + atomicAdd(&cnt2[src], 1u);
    bucket[pos] = e;
  }
}

// ---------------- K11: per-node gather softmax + weighted V accumulate -------
__global__ void rk_out(const int* __restrict__ ei, const float* __restrict__ ew,
                       const unsigned* __restrict__ offs, const unsigned* __restrict__ cnt,
                       const int* __restrict__ bucket, const float* __restrict__ Bmat,
                       const unsigned short* __restrict__ V, float* __restrict__ out) {
  const int n = blockIdx.x;
  const int t = threadIdx.x;      // 0..255
  const int l = t >> 2;           // 0..63
  const unsigned o0 = offs[n];
  const unsigned d = cnt[n];
  float m = -1e30f;
  for (unsigned i = 0; i < d; ++i) {
    const int e = bucket[o0 + i];
    const float logit = Bmat[ei[EE + e] * 64 + l] * ew[e];
    m = fmaxf(m, logit);
  }
  float s = 0.f, acc = 0.f;
  for (unsigned i = 0; i < d; ++i) {
    const int e = bucket[o0 + i];
    const int dst = ei[EE + e];
    const float p = expf(Bmat[dst * 64 + l] * ew[e] - m);
    s += p;
    acc += p * b2f(V[(size_t)dst * 256 + t]);
  }
  out[(size_t)n * 256 + t] = acc / (s + 1e-16f);
}

extern "C" void kernel_launch(void* const* d_in, const int* in_sizes, int n_in,
                              void* d_out, int out_size, void* d_ws, size_t ws_size,
                              hipStream_t stream) {
  const float* x       = (const float*)d_in[0];
  const float* p_t     = (const float*)d_in[1];
  const int*   ei      = (const int*)d_in[2];
  const float* ew      = (const float*)d_in[3];
  const float* W_value = (const float*)d_in[4];
  const float* b_value = (const float*)d_in[5];
  const float* W_inc   = (const float*)d_in[6];
  const float* b_inc   = (const float*)d_in[7];
  const float* mw      = (const float*)d_in[8];
  float* out = (float*)d_out;
  char* ws = (char*)d_ws;

  unsigned*           hist  = (unsigned*)(ws + O_HIST);
  unsigned*           meta  = (unsigned*)(ws + O_META);
  unsigned*           cnt   = (unsigned*)(ws + O_CNT);
  unsigned*           cnt2  = (unsigned*)(ws + O_CNT2);
  unsigned*           offs  = (unsigned*)(ws + O_OFFS);
  int*                buck  = (int*)(ws + O_BUCK);
  unsigned long long* keys  = (unsigned long long*)(ws + O_KEYS);
  int*                cand  = (int*)(ws + O_CAND);
  int*                sel   = (int*)(ws + O_SEL);
  double*             meanB = (double*)(ws + O_MEANB);
  float*              Bmat  = (float*)(ws + O_BMAT);
  unsigned short*     V     = (unsigned short*)(ws + O_V);
  unsigned short*     xb    = (unsigned short*)(ws + O_XB);
  unsigned short*     Wallt = (unsigned short*)(ws + O_WALLT);
  unsigned short*     Wvt   = (unsigned short*)(ws + O_WVT);
  double*             Wsum1 = (double*)(ws + O_WSUM1);
  double*             wsum2 = (double*)(ws + O_WSUM2);
  double*             bs1   = (double*)(ws + O_BS1);
  float*              cb    = (float*)(ws + O_CB);
  double*             cst   = (double*)(ws + O_CONST);

  hipMemsetAsync(ws, 0, ZERO_BYTES, stream);

  rk_prep<<<256, 64, 0, stream>>>(W_inc, p_t, b_inc, W_value, Wallt, Wvt,
                                  Wsum1, wsum2, bs1, cb, cst);
  rk_meanB<<<NN, 64, 0, stream>>>(x, mw, Wsum1, wsum2, bs1, cst, meanB, xb);
  rk_bmat<<<dim3(125, 4), 256, 0, stream>>>(xb, Wallt, mw, b_inc, cb, Bmat);
  rk_v<<<dim3(125, 4), 256, 0, stream>>>(xb, Wvt, b_value, V);
  rk_keys<<<250, 256, 0, stream>>>(ei, ew, meanB, keys, hist);
  rk_select<<<1, 1024, 0, stream>>>(hist, meta);
  rk_mark<<<250, 256, 0, stream>>>(keys, meta, cand, sel);
  rk_ties<<<1, 256, 0, stream>>>(keys, meta, cand, sel);
  rk_count<<<250, 256, 0, stream>>>(ei, sel, cnt);
  rk_scan<<<1, 1024, 0, stream>>>(cnt, offs);
  rk_fill<<<250, 256, 0, stream>>>(ei, sel, offs, cnt2, buck);
  rk_out<<<NN, 256, 0, stream>>>(ei, ew, offs, cnt, buck, Bmat, V, out);
}